// Round 4
// baseline (203.432 us; speedup 1.0000x reference)
//
#include <hip/hip_runtime.h>

// LocalPathEncoderRobustAdvancedTemporal — R7: stream-shaped writes, 4 samples/block.
// out[b,l,:] = (Σ_f relu(x_f*W1 + b1)) @ W2 + 8*b2   (8x FLOP collapse, exact)
//
// R5/R6 A/B exonerated store-instruction format (nt vs cached, 64B vs full-line:
// all ~193us). Remaining theory: write-pattern at DRAM level — 2048 short-lived
// blocks death-bursting 64KB each across two distant regions never reach
// streaming steady state (~2.2-2.5 TB/s vs fill's 6.3). R7:
//  * grid 512 x 4 consecutive samples/block -> 128KB contiguous write stream
//    per side per block, spread over block lifetime. Whole grid co-resident
//    (2 blocks/CU, ~74KB LDS).
//  * software-pipelined sample loop: prefetch s+1 ids/ts/scalars during stats;
//    s_tab re-zero overlapped with GEMM; 3 barriers/sample.
//  * w2t_prep dispatch eliminated: W2^T staged once per block into LDS
//    (af loads become ds_read_b128; one fewer launch in timed window).
//  * keeps R6 full-line LDS-transposed nt-store epilogue + verified numerics.

#define EPSF 1e-6f
#define LDB 136

typedef __attribute__((ext_vector_type(8))) short bf16x8;
typedef __attribute__((ext_vector_type(4))) float f32x4;
typedef __attribute__((ext_vector_type(2))) float f32x2;

__device__ inline short f2bf(float x) {           // fp32 -> bf16 (RNE)
    unsigned u = __float_as_uint(x);
    return (short)((u + 0x7fffu + ((u >> 16) & 1u)) >> 16);
}

__launch_bounds__(256, 2)
__global__ void lpe_fused4(const int* __restrict__ src_ids,
                           const int* __restrict__ dst_ids,
                           const int* __restrict__ src_nid,
                           const int* __restrict__ dst_nid,
                           const float* __restrict__ t_now,
                           const float* __restrict__ src_t,
                           const float* __restrict__ dst_t,
                           const float* __restrict__ W1,
                           const float* __restrict__ b1,
                           const float* __restrict__ W2,
                           const float* __restrict__ b2,
                           float* __restrict__ out)
{
    __shared__ int2  s_idt[128];                       // (id, t) per local row
    __shared__ __align__(16) f32x4 s_tab[2][512];      // per (side,id): n,avg,rec,last_t
    __shared__ float s_feats[128][9];                  // 8 feats, pad 9
    __shared__ __align__(16) float s_w1[128], s_b1[128], s_b2[128];
    __shared__ __align__(16) float s_stage[4][32][32]; // wave-private out staging
    __shared__ __align__(16) short W2T[128 * LDB];     // W2^T bf16, padded rows

    const int tid  = threadIdx.x;
    const int b4   = blockIdx.x * 4;                   // first of 4 samples
    const int lane = tid & 63, wv = tid >> 6;
    const int quad = lane >> 4, ln = lane & 15;
    const int side = (tid >> 6) & 1;                   // valid for tid<128
    const int i    = tid & 63;

    // ---- once per block: weights to LDS ----
    if (tid < 128) { s_w1[tid] = W1[tid]; s_b1[tid] = b1[tid]; s_b2[tid] = b2[tid]; }
    for (int u = tid; u < 16384; u += 256) {
        const int k = u >> 7, n = u & 127;
        W2T[n * LDB + k] = f2bf(W2[u]);
    }

    const int*   idp = side ? dst_ids : src_ids;
    const float* tp  = side ? dst_t   : src_t;

    // ---- prefetch sample 0 ----
    int   pf_id = 0; float pf_t = 0.f;
    if (tid < 128) { pf_id = idp[b4 * 64 + i]; pf_t = tp[b4 * 64 + i]; }
    float cur = t_now[b4];
    int   s_n = src_nid[b4], d_n = dst_nid[b4];

    // zero n-fields for sample 0 (other fields n>0-guarded)
    for (int u = tid; u < 1024; u += 256) ((float*)s_tab)[u * 4] = 0.f;

    const long side_stride = 2048L * 64L * 128L;

    for (int s = 0; s < 4; ++s) {
        const int   my_id = pf_id;  const float my_t = pf_t;
        const float curs  = cur;    const int sns = s_n, dns = d_n;
        if (tid < 128) s_idt[tid] = make_int2(my_id, __float_as_int(my_t));
        __syncthreads();                               // A: idt + tab-zero visible

        // ---- stats: n, tmax, tmin, rank, has-later (thr<128) ----
        float nf = 0.f, avg = 0.f;
        if (tid < 128) {
            int n = 0, rank = 0, later = 0;
            float tmax = -3.4e38f, tmin = 3.4e38f;
            const int sbase = side * 64;
            #pragma unroll 8
            for (int j = 0; j < 64; ++j) {
                const int2 e = s_idt[sbase + j];
                const float tj = __int_as_float(e.y);
                if (e.x == my_id) {
                    ++n;
                    tmax = fmaxf(tmax, tj);
                    tmin = fminf(tmin, tj);
                    if (tj < my_t || (tj == my_t && j < i)) ++rank;
                    if (j > i) later = 1;
                }
            }
            nf = (float)n;
            const int split = n >> 1;
            avg = (n > 1) ? (tmax - tmin) / (nf - 1.f) : 0.f;
            if (my_id != 0) {
                s_tab[side][my_id].x = nf;     // benign race: same value from members
                s_tab[side][my_id].y = avg;
                if (rank == split)             // unique: sorted(ts)[n//2] == my_t
                    s_tab[side][my_id].z = (n >= 4)
                        ? (tmax - my_t) / fmaxf(nf - (float)split - 1.f, 1.f) : 0.f;
                if (!later)                    // unique: last occurrence
                    s_tab[side][my_id].w = my_t;
            }
        }
        if (s < 3) {                           // ---- prefetch sample s+1 ----
            if (tid < 128) {
                pf_id = idp[(b4 + s + 1) * 64 + i];
                pf_t  = tp [(b4 + s + 1) * 64 + i];
            }
            cur = t_now[b4 + s + 1];
            s_n = src_nid[b4 + s + 1];
            d_n = dst_nid[b4 + s + 1];
        }
        __syncthreads();                               // B: tab visible

        // ---- cross features: O(1) table reads (thr<128) ----
        if (tid < 128) {
            const int os = side ^ 1;
            const float rec_m = (my_id != 0) ? s_tab[side][my_id].z : 0.f;
            const f32x4 to = s_tab[os][my_id];
            const float n_o = (my_id != 0) ? to.x : 0.f;
            const bool  hit = n_o > 0.f;
            const float avg_o = hit ? to.y : 0.f;
            const float rec_o = hit ? to.z : 0.f;
            const float lastt = hit ? to.w : 0.f;
            const int other_node = side ? sns : dns;
            const float m = (my_id != 0) ? 1.f : 0.f;

            const float rcy_s = curs - my_t;
            const float rcy_o = curs - lastt;
            s_feats[tid][0] = m * nf;
            s_feats[tid][1] = m * n_o;
            s_feats[tid][2] = m * ((my_id == other_node) ? 1.f : 0.f);
            s_feats[tid][3] = m * (hit ? 1.f : 0.f);
            s_feats[tid][4] = m * (hit ? nf / (n_o + EPSF) : 0.f);
            s_feats[tid][5] = m * ((rcy_s > EPSF) ? rcy_o / (rcy_s + EPSF) : 0.f);
            s_feats[tid][6] = m * ((avg_o > EPSF) ? avg / (avg_o + EPSF) : 0.f);
            s_feats[tid][7] = m * ((rec_o > EPSF) ? rec_m / (rec_o + EPSF) : 0.f);
        }
        __syncthreads();                               // C: feats visible

        // ---- GEMM: wave wv owns rows [wv*32, wv*32+32) ----
        float fxr[2][8];
        #pragma unroll
        for (int rg = 0; rg < 2; ++rg) {
            const int row = wv * 32 + rg * 16 + ln;
            #pragma unroll
            for (int j = 0; j < 8; ++j) fxr[rg][j] = s_feats[row][j];
        }
        if (s < 3)                              // re-zero tab for s+1 (overlaps GEMM)
            for (int u = tid; u < 1024; u += 256) ((float*)s_tab)[u * 4] = 0.f;

        bf16x8 gf[2][4];                        // g fragments [row-tile][k-block]
        #pragma unroll
        for (int kk = 0; kk < 4; ++kk) {
            const int kb = kk * 32 + quad * 8;
            #pragma unroll
            for (int rg = 0; rg < 2; ++rg) {
                #pragma unroll
                for (int u2 = 0; u2 < 4; ++u2) {
                    const f32x2 w  = *(const f32x2*)&s_w1[kb + u2 * 2];
                    const f32x2 bb = *(const f32x2*)&s_b1[kb + u2 * 2];
                    f32x2 sv = {0.f, 0.f};
                    #pragma unroll
                    for (int f = 0; f < 8; ++f) {
                        const f32x2 h = w * fxr[rg][f] + bb;   // v_pk_fma_f32
                        sv += __builtin_elementwise_max(h, (f32x2){0.f, 0.f});
                    }
                    gf[rg][kk][u2 * 2]     = f2bf(sv.x);
                    gf[rg][kk][u2 * 2 + 1] = f2bf(sv.y);
                }
            }
        }

        // ---- epilogue: et-pairs; stage 32x32 in wave-private LDS, read back
        //      linear -> each nt store = 1024B = 8 FULL 128B lines ----
        float* st = &s_stage[wv][0][0];
        const int sw = ln & 7;
        const long rowbase = (long)(b4 + s) * 64;

        #pragma unroll
        for (int p = 0; p < 4; ++p) {
            const int et0 = 2 * p, et1 = 2 * p + 1;
            bf16x8 afA[4], afB[4];
            #pragma unroll
            for (int kk = 0; kk < 4; ++kk) {
                afA[kk] = *(const bf16x8*)&W2T[(et0 * 16 + ln) * LDB + kk * 32 + quad * 8];
                afB[kk] = *(const bf16x8*)&W2T[(et1 * 16 + ln) * LDB + kk * 32 + quad * 8];
            }
            f32x4 accA[2] = {(f32x4){0.f,0.f,0.f,0.f}, (f32x4){0.f,0.f,0.f,0.f}};
            f32x4 accB[2] = {(f32x4){0.f,0.f,0.f,0.f}, (f32x4){0.f,0.f,0.f,0.f}};
            #pragma unroll
            for (int kk = 0; kk < 4; ++kk)
                #pragma unroll
                for (int rg = 0; rg < 2; ++rg) {
                    accA[rg] = __builtin_amdgcn_mfma_f32_16x16x32_bf16(afA[kk], gf[rg][kk], accA[rg], 0, 0, 0);
                    accB[rg] = __builtin_amdgcn_mfma_f32_16x16x32_bf16(afB[kk], gf[rg][kk], accB[rg], 0, 0, 0);
                }
            const f32x4 bA = *(const f32x4*)&s_b2[et0 * 16 + quad * 4] * 8.f;
            const f32x4 bB = *(const f32x4*)&s_b2[et1 * 16 + quad * 4] * 8.f;

            if (p)  // previous pair's LDS reads must finish before overwrite
                asm volatile("s_waitcnt lgkmcnt(0)" ::: "memory");
            #pragma unroll
            for (int rg = 0; rg < 2; ++rg) {
                const int row = rg * 16 + ln;
                *(f32x4*)&st[row * 32 + ((quad ^ sw) * 4)]       = accA[rg] + bA;
                *(f32x4*)&st[row * 32 + (((4 + quad) ^ sw) * 4)] = accB[rg] + bB;
            }
            asm volatile("s_waitcnt lgkmcnt(0)" ::: "memory");  // writes visible
            #pragma unroll
            for (int rr = 0; rr < 4; ++rr) {
                const int rl = rr * 8 + (lane >> 3);             // local row 0..31
                const f32x4 v = *(const f32x4*)&st[rl * 32 + (((lane & 7) ^ (rl & 7)) * 4)];
                const int row = wv * 32 + rl;
                const int sd = row >> 6, ii = row & 63;
                __builtin_nontemporal_store(v,
                    (f32x4*)&out[(long)sd * side_stride + (rowbase + ii) * 128
                                 + p * 32 + (lane & 7) * 4]);
            }
        }
        // next iteration's barrier A orders: tab-zero + idt-write vs stats reads;
        // its implicit waitcnt also drains this sample's LDS epilogue reads.
    }
}

extern "C" void kernel_launch(void* const* d_in, const int* in_sizes, int n_in,
                              void* d_out, int out_size, void* d_ws, size_t ws_size,
                              hipStream_t stream) {
    (void)in_sizes; (void)n_in; (void)out_size; (void)d_ws; (void)ws_size;
    const int*   src_ids = (const int*)  d_in[0];
    const int*   dst_ids = (const int*)  d_in[1];
    const int*   src_nid = (const int*)  d_in[2];
    const int*   dst_nid = (const int*)  d_in[3];
    const float* t_now   = (const float*)d_in[4];
    const float* src_t   = (const float*)d_in[5];
    const float* dst_t   = (const float*)d_in[6];
    const float* W1      = (const float*)d_in[7];
    const float* b1      = (const float*)d_in[8];
    const float* W2      = (const float*)d_in[9];
    const float* b2      = (const float*)d_in[10];
    float* out = (float*)d_out;

    lpe_fused4<<<512, 256, 0, stream>>>(src_ids, dst_ids, src_nid, dst_nid,
                                        t_now, src_t, dst_t, W1, b1, W2, b2, out);
}

// Round 5
// 185.304 us; speedup vs baseline: 1.0978x; 1.0978x over previous
//
#include <hip/hip_runtime.h>

// LocalPathEncoderRobustAdvancedTemporal — R8: split into fill-shaped writer.
// out[b,l,:] = (Σ_f relu(x_f*W1 + b1)) @ W2 + 8*b2   (8x FLOP collapse, exact)
//
// R4-R7: four orthogonal write-path fixes all null (193-203us). Window
// decomposition: fill(~85, fixed) + restores(~30, fixed) + lpe(~75-85, stuck).
// Surviving theory: stores issue in short end-of-sample bursts gated by
// {barrier -> MFMA -> LDS}, never reaching streaming depth (fill sustains
// 6.3 TB/s with barrier-free back-to-back full-line stores). R8 splits:
//  * k1 (2048 x 128thr, 17KB LDS, high occ): stats + features -> compact
//    8-f32 vectors to ws (8.4 MB). Verified feature code verbatim.
//  * k2 (2048 x 256thr): pure streaming GEMM. Reads feats, first-layer in
//    registers (verified pk-fma), MFMA vs LDS W2^T, R6 full-line transposed
//    nt epilogue. 64KB contiguous/block, NO per-sample barriers — waves
//    stream stores continuously, fill-like.
//  * traffic 163MB -> 26us floor; numerics bit-identical to R7.
//  * ws fallback: R7 fused kernel if ws too small.

#define EPSF 1e-6f
#define LDB 136

typedef __attribute__((ext_vector_type(8))) short bf16x8;
typedef __attribute__((ext_vector_type(4))) float f32x4;
typedef __attribute__((ext_vector_type(2))) float f32x2;

__device__ inline short f2bf(float x) {           // fp32 -> bf16 (RNE)
    unsigned u = __float_as_uint(x);
    return (short)((u + 0x7fffu + ((u >> 16) & 1u)) >> 16);
}

__global__ void w2t_prep(const float* __restrict__ W2, short* __restrict__ w2t) {
    const int idx = blockIdx.x * 256 + threadIdx.x;   // 16384
    const int k = idx >> 7, n = idx & 127;
    w2t[n * 128 + k] = f2bf(W2[idx]);
}

// ---------------- k1: stats + cross features -> feats[2][2048][64][8] ----------------
__launch_bounds__(128)
__global__ void lpe_feats(const int* __restrict__ src_ids,
                          const int* __restrict__ dst_ids,
                          const int* __restrict__ src_nid,
                          const int* __restrict__ dst_nid,
                          const float* __restrict__ t_now,
                          const float* __restrict__ src_t,
                          const float* __restrict__ dst_t,
                          float* __restrict__ fs)
{
    __shared__ int2  s_idt[128];                  // (id, t) per local row
    __shared__ __align__(16) f32x4 s_tab[2][512]; // per (side,id): n,avg,rec,last_t

    const int tid  = threadIdx.x;                 // 0..127
    const int b    = blockIdx.x;                  // one sample per block
    const int side = tid >> 6;
    const int i    = tid & 63;

    // zero n-fields (other fields are n>0-guarded)
    #pragma unroll
    for (int u = tid; u < 1024; u += 128) ((float*)s_tab)[u * 4] = 0.f;

    const float cur = t_now[b];
    const int   s_n = src_nid[b], d_n = dst_nid[b];

    const int*   idp = side ? dst_ids : src_ids;
    const float* tp  = side ? dst_t   : src_t;
    const int   my_id = idp[b * 64 + i];
    const float my_t  = tp [b * 64 + i];
    s_idt[tid] = make_int2(my_id, __float_as_int(my_t));
    __syncthreads();

    // ---- stats: n, tmax, tmin, rank, has-later ----
    int n = 0, rank = 0, later = 0;
    float tmax = -3.4e38f, tmin = 3.4e38f;
    const int sbase = side * 64;
    #pragma unroll 8
    for (int j = 0; j < 64; ++j) {
        const int2 e = s_idt[sbase + j];
        const float tj = __int_as_float(e.y);
        if (e.x == my_id) {
            ++n;
            tmax = fmaxf(tmax, tj);
            tmin = fminf(tmin, tj);
            if (tj < my_t || (tj == my_t && j < i)) ++rank;
            if (j > i) later = 1;
        }
    }
    const float nf    = (float)n;
    const int   split = n >> 1;
    const float avg   = (n > 1) ? (tmax - tmin) / (nf - 1.f) : 0.f;
    if (my_id != 0) {
        s_tab[side][my_id].x = nf;     // benign race: same value from all members
        s_tab[side][my_id].y = avg;
        if (rank == split)             // unique member: sorted(ts)[n//2] == my_t
            s_tab[side][my_id].z = (n >= 4)
                ? (tmax - my_t) / fmaxf(nf - (float)split - 1.f, 1.f) : 0.f;
        if (!later)                    // unique member: last occurrence
            s_tab[side][my_id].w = my_t;
    }
    __syncthreads();

    // ---- cross features: O(1) table reads ----
    const int os = side ^ 1;
    const float rec_m = (my_id != 0) ? s_tab[side][my_id].z : 0.f;
    const f32x4 to = s_tab[os][my_id];
    const float n_o = (my_id != 0) ? to.x : 0.f;
    const bool  hit = n_o > 0.f;
    const float avg_o = hit ? to.y : 0.f;
    const float rec_o = hit ? to.z : 0.f;
    const float lastt = hit ? to.w : 0.f;
    const int other_node = side ? s_n : d_n;
    const float m = (my_id != 0) ? 1.f : 0.f;

    const float rcy_s = cur - my_t;
    const float rcy_o = cur - lastt;
    f32x4 f0, f1;
    f0.x = m * nf;
    f0.y = m * n_o;
    f0.z = m * ((my_id == other_node) ? 1.f : 0.f);
    f0.w = m * (hit ? 1.f : 0.f);
    f1.x = m * (hit ? nf / (n_o + EPSF) : 0.f);
    f1.y = m * ((rcy_s > EPSF) ? rcy_o / (rcy_s + EPSF) : 0.f);
    f1.z = m * ((avg_o > EPSF) ? avg / (avg_o + EPSF) : 0.f);
    f1.w = m * ((rec_o > EPSF) ? rec_m / (rec_o + EPSF) : 0.f);

    const long rowf = (long)side * 131072 + (long)b * 64 + i;   // [side][b][l]
    *(f32x4*)&fs[rowf * 8]     = f0;
    *(f32x4*)&fs[rowf * 8 + 4] = f1;
}

// ---------------- k2: streaming first-layer + GEMM + full-line writer ----------------
__launch_bounds__(256, 3)
__global__ void lpe_gemm(const float* __restrict__ fs,
                         const short* __restrict__ w2t,
                         const float* __restrict__ W1,
                         const float* __restrict__ b1,
                         const float* __restrict__ b2,
                         float* __restrict__ out)
{
    __shared__ __align__(16) float s_w1[128], s_b1[128], s_b2[128];
    __shared__ __align__(16) short W2T[128 * LDB];     // W2^T bf16, padded rows
    __shared__ __align__(16) float s_stage[4][32][32]; // wave-private out staging

    const int tid  = threadIdx.x;
    const int lane = tid & 63, wv = tid >> 6;
    const int quad = lane >> 4, ln = lane & 15;

    // stage W2^T (bf16, pre-converted) into padded LDS rows: 16B chunks
    #pragma unroll
    for (int it = 0; it < 8; ++it) {
        const int c = tid + it * 256;              // 2048 chunks of 8 shorts
        const int n = c >> 4, j = c & 15;
        *(bf16x8*)&W2T[n * LDB + j * 8] = *(const bf16x8*)&w2t[n * 128 + j * 8];
    }
    if (tid < 128) { s_w1[tid] = W1[tid]; s_b1[tid] = b1[tid]; s_b2[tid] = b2[tid]; }
    __syncthreads();

    const long base = (long)blockIdx.x * 128;      // 128 flat rows per block

    // ---- load feats for this wave's 32 rows ----
    float fxr[2][8];
    #pragma unroll
    for (int rg = 0; rg < 2; ++rg) {
        const long rowf = base + wv * 32 + rg * 16 + ln;
        const f32x4 a = *(const f32x4*)&fs[rowf * 8];
        const f32x4 c = *(const f32x4*)&fs[rowf * 8 + 4];
        fxr[rg][0] = a.x; fxr[rg][1] = a.y; fxr[rg][2] = a.z; fxr[rg][3] = a.w;
        fxr[rg][4] = c.x; fxr[rg][5] = c.y; fxr[rg][6] = c.z; fxr[rg][7] = c.w;
    }

    // ---- first layer: g = sum_f relu(x_f*W1+b1), bf16 fragments ----
    bf16x8 gf[2][4];                               // [row-tile][k-block]
    #pragma unroll
    for (int kk = 0; kk < 4; ++kk) {
        const int kb = kk * 32 + quad * 8;
        #pragma unroll
        for (int rg = 0; rg < 2; ++rg) {
            #pragma unroll
            for (int u2 = 0; u2 < 4; ++u2) {
                const f32x2 w  = *(const f32x2*)&s_w1[kb + u2 * 2];
                const f32x2 bb = *(const f32x2*)&s_b1[kb + u2 * 2];
                f32x2 sv = {0.f, 0.f};
                #pragma unroll
                for (int f = 0; f < 8; ++f) {
                    const f32x2 h = w * fxr[rg][f] + bb;      // v_pk_fma_f32
                    sv += __builtin_elementwise_max(h, (f32x2){0.f, 0.f});
                }
                gf[rg][kk][u2 * 2]     = f2bf(sv.x);
                gf[rg][kk][u2 * 2 + 1] = f2bf(sv.y);
            }
        }
    }

    // ---- GEMM + full-line transposed epilogue (verified R6 structure) ----
    float* st = &s_stage[wv][0][0];
    const int sw = ln & 7;

    #pragma unroll
    for (int p = 0; p < 4; ++p) {
        const int et0 = 2 * p, et1 = 2 * p + 1;
        bf16x8 afA[4], afB[4];
        #pragma unroll
        for (int kk = 0; kk < 4; ++kk) {
            afA[kk] = *(const bf16x8*)&W2T[(et0 * 16 + ln) * LDB + kk * 32 + quad * 8];
            afB[kk] = *(const bf16x8*)&W2T[(et1 * 16 + ln) * LDB + kk * 32 + quad * 8];
        }
        f32x4 accA[2] = {(f32x4){0.f,0.f,0.f,0.f}, (f32x4){0.f,0.f,0.f,0.f}};
        f32x4 accB[2] = {(f32x4){0.f,0.f,0.f,0.f}, (f32x4){0.f,0.f,0.f,0.f}};
        #pragma unroll
        for (int kk = 0; kk < 4; ++kk)
            #pragma unroll
            for (int rg = 0; rg < 2; ++rg) {
                accA[rg] = __builtin_amdgcn_mfma_f32_16x16x32_bf16(afA[kk], gf[rg][kk], accA[rg], 0, 0, 0);
                accB[rg] = __builtin_amdgcn_mfma_f32_16x16x32_bf16(afB[kk], gf[rg][kk], accB[rg], 0, 0, 0);
            }
        const f32x4 bA = *(const f32x4*)&s_b2[et0 * 16 + quad * 4] * 8.f;
        const f32x4 bB = *(const f32x4*)&s_b2[et1 * 16 + quad * 4] * 8.f;

        if (p)  // previous pair's LDS reads must finish before overwrite
            asm volatile("s_waitcnt lgkmcnt(0)" ::: "memory");
        #pragma unroll
        for (int rg = 0; rg < 2; ++rg) {
            const int row = rg * 16 + ln;
            *(f32x4*)&st[row * 32 + ((quad ^ sw) * 4)]       = accA[rg] + bA;
            *(f32x4*)&st[row * 32 + (((4 + quad) ^ sw) * 4)] = accB[rg] + bB;
        }
        asm volatile("s_waitcnt lgkmcnt(0)" ::: "memory");  // writes visible
        #pragma unroll
        for (int rr = 0; rr < 4; ++rr) {
            const int rl = rr * 8 + (lane >> 3);             // local row 0..31
            const f32x4 v = *(const f32x4*)&st[rl * 32 + (((lane & 7) ^ (rl & 7)) * 4)];
            const long rowf = base + wv * 32 + rl;
            __builtin_nontemporal_store(v,
                (f32x4*)&out[rowf * 128 + p * 32 + (lane & 7) * 4]);
        }
    }
}

// ---------------- fallback: R7 fused (ws too small) ----------------
__launch_bounds__(256, 2)
__global__ void lpe_fused4(const int* __restrict__ src_ids,
                           const int* __restrict__ dst_ids,
                           const int* __restrict__ src_nid,
                           const int* __restrict__ dst_nid,
                           const float* __restrict__ t_now,
                           const float* __restrict__ src_t,
                           const float* __restrict__ dst_t,
                           const float* __restrict__ W1,
                           const float* __restrict__ b1,
                           const float* __restrict__ W2,
                           const float* __restrict__ b2,
                           float* __restrict__ out)
{
    __shared__ int2  s_idt[128];
    __shared__ __align__(16) f32x4 s_tab[2][512];
    __shared__ float s_feats[128][9];
    __shared__ __align__(16) float s_w1[128], s_b1[128], s_b2[128];
    __shared__ __align__(16) float s_stage[4][32][32];
    __shared__ __align__(16) short W2T[128 * LDB];

    const int tid  = threadIdx.x;
    const int b4   = blockIdx.x * 4;
    const int lane = tid & 63, wv = tid >> 6;
    const int quad = lane >> 4, ln = lane & 15;
    const int side = (tid >> 6) & 1;
    const int i    = tid & 63;

    if (tid < 128) { s_w1[tid] = W1[tid]; s_b1[tid] = b1[tid]; s_b2[tid] = b2[tid]; }
    for (int u = tid; u < 16384; u += 256) {
        const int k = u >> 7, n = u & 127;
        W2T[n * LDB + k] = f2bf(W2[u]);
    }
    const int*   idp = side ? dst_ids : src_ids;
    const float* tp  = side ? dst_t   : src_t;
    int   pf_id = 0; float pf_t = 0.f;
    if (tid < 128) { pf_id = idp[b4 * 64 + i]; pf_t = tp[b4 * 64 + i]; }
    float cur = t_now[b4];
    int   s_n = src_nid[b4], d_n = dst_nid[b4];
    for (int u = tid; u < 1024; u += 256) ((float*)s_tab)[u * 4] = 0.f;
    const long side_stride = 2048L * 64L * 128L;

    for (int s = 0; s < 4; ++s) {
        const int   my_id = pf_id;  const float my_t = pf_t;
        const float curs  = cur;    const int sns = s_n, dns = d_n;
        if (tid < 128) s_idt[tid] = make_int2(my_id, __float_as_int(my_t));
        __syncthreads();

        float nf = 0.f, avg = 0.f;
        if (tid < 128) {
            int n = 0, rank = 0, later = 0;
            float tmax = -3.4e38f, tmin = 3.4e38f;
            const int sbase = side * 64;
            #pragma unroll 8
            for (int j = 0; j < 64; ++j) {
                const int2 e = s_idt[sbase + j];
                const float tj = __int_as_float(e.y);
                if (e.x == my_id) {
                    ++n; tmax = fmaxf(tmax, tj); tmin = fminf(tmin, tj);
                    if (tj < my_t || (tj == my_t && j < i)) ++rank;
                    if (j > i) later = 1;
                }
            }
            nf = (float)n;
            const int split = n >> 1;
            avg = (n > 1) ? (tmax - tmin) / (nf - 1.f) : 0.f;
            if (my_id != 0) {
                s_tab[side][my_id].x = nf;
                s_tab[side][my_id].y = avg;
                if (rank == split)
                    s_tab[side][my_id].z = (n >= 4)
                        ? (tmax - my_t) / fmaxf(nf - (float)split - 1.f, 1.f) : 0.f;
                if (!later) s_tab[side][my_id].w = my_t;
            }
        }
        if (s < 3) {
            if (tid < 128) {
                pf_id = idp[(b4 + s + 1) * 64 + i];
                pf_t  = tp [(b4 + s + 1) * 64 + i];
            }
            cur = t_now[b4 + s + 1];
            s_n = src_nid[b4 + s + 1];
            d_n = dst_nid[b4 + s + 1];
        }
        __syncthreads();

        if (tid < 128) {
            const int os = side ^ 1;
            const float rec_m = (my_id != 0) ? s_tab[side][my_id].z : 0.f;
            const f32x4 to = s_tab[os][my_id];
            const float n_o = (my_id != 0) ? to.x : 0.f;
            const bool  hit = n_o > 0.f;
            const float avg_o = hit ? to.y : 0.f;
            const float rec_o = hit ? to.z : 0.f;
            const float lastt = hit ? to.w : 0.f;
            const int other_node = side ? sns : dns;
            const float m = (my_id != 0) ? 1.f : 0.f;
            const float rcy_s = curs - my_t;
            const float rcy_o = curs - lastt;
            s_feats[tid][0] = m * nf;
            s_feats[tid][1] = m * n_o;
            s_feats[tid][2] = m * ((my_id == other_node) ? 1.f : 0.f);
            s_feats[tid][3] = m * (hit ? 1.f : 0.f);
            s_feats[tid][4] = m * (hit ? nf / (n_o + EPSF) : 0.f);
            s_feats[tid][5] = m * ((rcy_s > EPSF) ? rcy_o / (rcy_s + EPSF) : 0.f);
            s_feats[tid][6] = m * ((avg_o > EPSF) ? avg / (avg_o + EPSF) : 0.f);
            s_feats[tid][7] = m * ((rec_o > EPSF) ? rec_m / (rec_o + EPSF) : 0.f);
        }
        __syncthreads();

        float fxr[2][8];
        #pragma unroll
        for (int rg = 0; rg < 2; ++rg) {
            const int row = wv * 32 + rg * 16 + ln;
            #pragma unroll
            for (int j = 0; j < 8; ++j) fxr[rg][j] = s_feats[row][j];
        }
        if (s < 3)
            for (int u = tid; u < 1024; u += 256) ((float*)s_tab)[u * 4] = 0.f;

        bf16x8 gf[2][4];
        #pragma unroll
        for (int kk = 0; kk < 4; ++kk) {
            const int kb = kk * 32 + quad * 8;
            #pragma unroll
            for (int rg = 0; rg < 2; ++rg) {
                #pragma unroll
                for (int u2 = 0; u2 < 4; ++u2) {
                    const f32x2 w  = *(const f32x2*)&s_w1[kb + u2 * 2];
                    const f32x2 bb = *(const f32x2*)&s_b1[kb + u2 * 2];
                    f32x2 sv = {0.f, 0.f};
                    #pragma unroll
                    for (int f = 0; f < 8; ++f) {
                        const f32x2 h = w * fxr[rg][f] + bb;
                        sv += __builtin_elementwise_max(h, (f32x2){0.f, 0.f});
                    }
                    gf[rg][kk][u2 * 2]     = f2bf(sv.x);
                    gf[rg][kk][u2 * 2 + 1] = f2bf(sv.y);
                }
            }
        }

        float* st = &s_stage[wv][0][0];
        const int sw = ln & 7;
        const long rowbase = (long)(b4 + s) * 64;

        #pragma unroll
        for (int p = 0; p < 4; ++p) {
            const int et0 = 2 * p, et1 = 2 * p + 1;
            bf16x8 afA[4], afB[4];
            #pragma unroll
            for (int kk = 0; kk < 4; ++kk) {
                afA[kk] = *(const bf16x8*)&W2T[(et0 * 16 + ln) * LDB + kk * 32 + quad * 8];
                afB[kk] = *(const bf16x8*)&W2T[(et1 * 16 + ln) * LDB + kk * 32 + quad * 8];
            }
            f32x4 accA[2] = {(f32x4){0.f,0.f,0.f,0.f}, (f32x4){0.f,0.f,0.f,0.f}};
            f32x4 accB[2] = {(f32x4){0.f,0.f,0.f,0.f}, (f32x4){0.f,0.f,0.f,0.f}};
            #pragma unroll
            for (int kk = 0; kk < 4; ++kk)
                #pragma unroll
                for (int rg = 0; rg < 2; ++rg) {
                    accA[rg] = __builtin_amdgcn_mfma_f32_16x16x32_bf16(afA[kk], gf[rg][kk], accA[rg], 0, 0, 0);
                    accB[rg] = __builtin_amdgcn_mfma_f32_16x16x32_bf16(afB[kk], gf[rg][kk], accB[rg], 0, 0, 0);
                }
            const f32x4 bA = *(const f32x4*)&s_b2[et0 * 16 + quad * 4] * 8.f;
            const f32x4 bB = *(const f32x4*)&s_b2[et1 * 16 + quad * 4] * 8.f;

            if (p)
                asm volatile("s_waitcnt lgkmcnt(0)" ::: "memory");
            #pragma unroll
            for (int rg = 0; rg < 2; ++rg) {
                const int row = rg * 16 + ln;
                *(f32x4*)&st[row * 32 + ((quad ^ sw) * 4)]       = accA[rg] + bA;
                *(f32x4*)&st[row * 32 + (((4 + quad) ^ sw) * 4)] = accB[rg] + bB;
            }
            asm volatile("s_waitcnt lgkmcnt(0)" ::: "memory");
            #pragma unroll
            for (int rr = 0; rr < 4; ++rr) {
                const int rl = rr * 8 + (lane >> 3);
                const f32x4 v = *(const f32x4*)&st[rl * 32 + (((lane & 7) ^ (rl & 7)) * 4)];
                const int row = wv * 32 + rl;
                const int sd = row >> 6, ii = row & 63;
                __builtin_nontemporal_store(v,
                    (f32x4*)&out[(long)sd * side_stride + (rowbase + ii) * 128
                                 + p * 32 + (lane & 7) * 4]);
            }
        }
    }
}

extern "C" void kernel_launch(void* const* d_in, const int* in_sizes, int n_in,
                              void* d_out, int out_size, void* d_ws, size_t ws_size,
                              hipStream_t stream) {
    (void)in_sizes; (void)n_in; (void)out_size;
    const int*   src_ids = (const int*)  d_in[0];
    const int*   dst_ids = (const int*)  d_in[1];
    const int*   src_nid = (const int*)  d_in[2];
    const int*   dst_nid = (const int*)  d_in[3];
    const float* t_now   = (const float*)d_in[4];
    const float* src_t   = (const float*)d_in[5];
    const float* dst_t   = (const float*)d_in[6];
    const float* W1      = (const float*)d_in[7];
    const float* b1      = (const float*)d_in[8];
    const float* W2      = (const float*)d_in[9];
    const float* b2      = (const float*)d_in[10];
    float* out = (float*)d_out;

    // ws layout: [0, 32KB) w2t bf16; [32KB, 32KB + 8.39MB) feats f32
    const size_t W2T_BYTES  = 128 * 128 * sizeof(short);
    const size_t FEAT_BYTES = 262144ULL * 8 * sizeof(float);

    if (ws_size >= W2T_BYTES + FEAT_BYTES) {
        short* w2t = (short*)d_ws;
        float* fs  = (float*)((char*)d_ws + W2T_BYTES);
        w2t_prep<<<64, 256, 0, stream>>>(W2, w2t);
        lpe_feats<<<2048, 128, 0, stream>>>(src_ids, dst_ids, src_nid, dst_nid,
                                            t_now, src_t, dst_t, fs);
        lpe_gemm<<<2048, 256, 0, stream>>>(fs, w2t, W1, b1, b2, out);
    } else {
        lpe_fused4<<<512, 256, 0, stream>>>(src_ids, dst_ids, src_nid, dst_nid,
                                            t_now, src_t, dst_t, W1, b1, W2, b2, out);
    }
}